// Round 1
// baseline (131121.118 us; speedup 1.0000x reference)
//
#include <hip/hip_runtime.h>
#include <math.h>

// Problem constants
#define BB   256   // batch
#define TT   1024  // timesteps
#define HH   512   // hidden
#define NWG  512   // one workgroup per hidden column
#define NTHR 256   // one thread per batch element
#define HB   (HH*BB)

// ---------------- grid barrier (all 512 WGs co-resident: 256 CUs, <=2 blk/CU by LDS/waves) ----
__device__ __forceinline__ void gridbar(unsigned* cnt, unsigned target){
  __syncthreads();
  if (threadIdx.x == 0){
    __builtin_amdgcn_fence(__ATOMIC_RELEASE, "agent");
    __hip_atomic_fetch_add(cnt, 1u, __ATOMIC_RELAXED, __HIP_MEMORY_SCOPE_AGENT);
    while (__hip_atomic_load(cnt, __ATOMIC_RELAXED, __HIP_MEMORY_SCOPE_AGENT) < target){
      __builtin_amdgcn_s_sleep(1);
    }
    __builtin_amdgcn_fence(__ATOMIC_ACQUIRE, "agent");
  }
  __syncthreads();
}

__device__ __forceinline__ float fast_sigmoid(float v){
  float e = __expf(-v);
  return __builtin_amdgcn_rcpf(1.0f + e);
}
__device__ __forceinline__ float fast_tanh(float v){
  float a = fabsf(v);
  float e = __expf(-2.0f * a);
  float r = (1.0f - e) * __builtin_amdgcn_rcpf(1.0f + e);
  return copysignf(r, v);
}

// ws float layout: [0..15] barrier counter (+pad), [16..) xT (B*T), then h1 dbl buf, h2 dbl buf
__global__ __launch_bounds__(NTHR, 2) void lstm_persistent(
    const float* __restrict__ x,      // [B,T]
    const float* __restrict__ W_ih1,  // [4H,1]
    const float* __restrict__ W_hh1,  // [4H,H]
    const float* __restrict__ b1,     // [4H]
    const float* __restrict__ W_ih2,  // [4H,H]
    const float* __restrict__ W_hh2,  // [4H,H]
    const float* __restrict__ b2,     // [4H]
    const float* __restrict__ W_lin,  // [1,H]
    const float* __restrict__ b_lin,  // [1]
    float* __restrict__ out,          // [B,T]
    float* __restrict__ ws)
{
  unsigned* bar_cnt = (unsigned*)ws;
  float* xT    = ws + 16;            // [T][B]
  float* h1buf = xT + BB*TT;         // 2 x [H][B]
  float* h2buf = h1buf + 2*HB;       // 2 x [H][B]

  const int wg  = blockIdx.x;        // hidden column j = wg
  const int tid = threadIdx.x;       // batch b = tid

  // LDS-stationary weights: 4 gate-rows per matrix for column wg
  __shared__ float wA[4][HH];   // W_hh1 rows g*H+wg
  __shared__ float wI[4][HH];   // W_ih2 rows g*H+wg
  __shared__ float wH[4][HH];   // W_hh2 rows g*H+wg
  __shared__ float wlin_s[HH];  // used by wg < 256 only
  __shared__ float red4[4];

  #pragma unroll
  for (int g = 0; g < 4; ++g){
    const int row = g*HH + wg;
    for (int k = tid; k < HH; k += NTHR){
      wA[g][k] = W_hh1[row*HH + k];
      wI[g][k] = W_ih2[row*HH + k];
      wH[g][k] = W_hh2[row*HH + k];
    }
  }
  if (wg < BB){
    for (int k = tid; k < HH; k += NTHR) wlin_s[k] = W_lin[k];
  }

  // per-WG scalar constants (uniform -> SGPRs)
  float b1r[4], wih1r[4], b2r[4];
  #pragma unroll
  for (int g = 0; g < 4; ++g){
    b1r[g]   = b1[g*HH + wg];
    wih1r[g] = W_ih1[g*HH + wg];
    b2r[g]   = b2[g*HH + wg];
  }
  const float blin = b_lin[0];

  // transpose x -> xT[t][b] (coalesced reads)
  {
    const int gid = wg*NTHR + tid;            // 0..131071
    #pragma unroll
    for (int i = 0; i < 2; ++i){
      const int idx = gid + i*131072;         // = b*T + t
      const int bb = idx >> 10, t = idx & (TT-1);
      xT[t*BB + bb] = x[idx];
    }
  }
  // zero h state (own column in both parity buffers)
  h1buf[0*HB + wg*BB + tid] = 0.0f;
  h1buf[1*HB + wg*BB + tid] = 0.0f;
  h2buf[0*HB + wg*BB + tid] = 0.0f;
  h2buf[1*HB + wg*BB + tid] = 0.0f;

  float c1 = 0.0f, c2 = 0.0f;
  unsigned bar_target = 0;
  bar_target += NWG; gridbar(bar_cnt, bar_target);

  const int b = tid;

  for (int t = 0; t < TT; ++t){
    const float* h1prev = h1buf + ((t+1)&1)*HB;  // h1(t-1)
    float*       h1cur  = h1buf + (t&1)*HB;      // h1(t)
    const float* h2prev = h2buf + ((t+1)&1)*HB;  // h2(t-1)
    float*       h2cur  = h2buf + (t&1)*HB;      // h2(t)

    // ---------------- phase A: layer-1 cell + out(t-1) ----------------
    float osum = 0.0f;
    if (wg < BB && t > 0){
      osum = fmaf(h2prev[tid*BB + wg],      wlin_s[tid],
             h2prev[(tid+BB)*BB + wg] * wlin_s[tid+BB]);
    }

    float a0=0.f, a1=0.f, a2=0.f, a3=0.f;
    {
      const float* hp = h1prev + b;
      #pragma unroll 8
      for (int k = 0; k < HH; ++k){
        const float hv = hp[k*BB];
        a0 = fmaf(wA[0][k], hv, a0);
        a1 = fmaf(wA[1][k], hv, a1);
        a2 = fmaf(wA[2][k], hv, a2);
        a3 = fmaf(wA[3][k], hv, a3);
      }
    }
    const float xv = xT[t*BB + b];
    const float gi = fast_sigmoid(fmaf(xv, wih1r[0], a0) + b1r[0]);
    const float gf = fast_sigmoid(fmaf(xv, wih1r[1], a1) + b1r[1]);
    const float gg = fast_tanh   (fmaf(xv, wih1r[2], a2) + b1r[2]);
    const float go = fast_sigmoid(fmaf(xv, wih1r[3], a3) + b1r[3]);
    c1 = fmaf(gf, c1, gi*gg);
    h1cur[wg*BB + b] = go * fast_tanh(c1);

    if (wg < BB && t > 0){
      #pragma unroll
      for (int off = 32; off > 0; off >>= 1) osum += __shfl_down(osum, off, 64);
      if ((tid & 63) == 0) red4[tid >> 6] = osum;
      __syncthreads();
      if (tid == 0) out[wg*TT + (t-1)] = red4[0]+red4[1]+red4[2]+red4[3] + blin;
    }

    bar_target += NWG; gridbar(bar_cnt, bar_target);

    // ---------------- phase B: layer-2 cell ----------------
    float d0=0.f, d1=0.f, d2=0.f, d3=0.f;
    {
      const float* hp1 = h1cur + b;
      const float* hp2 = h2prev + b;
      #pragma unroll 4
      for (int k = 0; k < HH; ++k){
        const float h1k = hp1[k*BB];
        const float h2k = hp2[k*BB];
        d0 = fmaf(wI[0][k], h1k, d0);  d0 = fmaf(wH[0][k], h2k, d0);
        d1 = fmaf(wI[1][k], h1k, d1);  d1 = fmaf(wH[1][k], h2k, d1);
        d2 = fmaf(wI[2][k], h1k, d2);  d2 = fmaf(wH[2][k], h2k, d2);
        d3 = fmaf(wI[3][k], h1k, d3);  d3 = fmaf(wH[3][k], h2k, d3);
      }
    }
    const float i2 = fast_sigmoid(d0 + b2r[0]);
    const float f2 = fast_sigmoid(d1 + b2r[1]);
    const float g2 = fast_tanh   (d2 + b2r[2]);
    const float o2 = fast_sigmoid(d3 + b2r[3]);
    c2 = fmaf(f2, c2, i2*g2);
    h2cur[wg*BB + b] = o2 * fast_tanh(c2);

    bar_target += NWG; gridbar(bar_cnt, bar_target);
  }

  // epilogue: out(T-1)
  if (wg < BB){
    const float* h2last = h2buf + ((TT-1)&1)*HB;
    float s = fmaf(h2last[tid*BB + wg],      wlin_s[tid],
              h2last[(tid+BB)*BB + wg] * wlin_s[tid+BB]);
    #pragma unroll
    for (int off = 32; off > 0; off >>= 1) s += __shfl_down(s, off, 64);
    if ((tid & 63) == 0) red4[tid >> 6] = s;
    __syncthreads();
    if (tid == 0) out[wg*TT + (TT-1)] = red4[0]+red4[1]+red4[2]+red4[3] + blin;
  }
}

extern "C" void kernel_launch(void* const* d_in, const int* in_sizes, int n_in,
                              void* d_out, int out_size, void* d_ws, size_t ws_size,
                              hipStream_t stream) {
  const float* x     = (const float*)d_in[0];
  const float* W_ih1 = (const float*)d_in[1];
  const float* W_hh1 = (const float*)d_in[2];
  const float* b1    = (const float*)d_in[3];
  const float* W_ih2 = (const float*)d_in[4];
  const float* W_hh2 = (const float*)d_in[5];
  const float* b2    = (const float*)d_in[6];
  const float* W_lin = (const float*)d_in[7];
  const float* b_lin = (const float*)d_in[8];
  float* out = (float*)d_out;
  float* ws  = (float*)d_ws;

  // zero the barrier counter (ws is re-poisoned to 0xAA before every launch)
  hipMemsetAsync(d_ws, 0, 64, stream);

  hipLaunchKernelGGL(lstm_persistent, dim3(NWG), dim3(NTHR), 0, stream,
                     x, W_ih1, W_hh1, b1, W_ih2, W_hh2, b2, W_lin, b_lin, out, ws);
}

// Round 2
// 26952.765 us; speedup vs baseline: 4.8648x; 4.8648x over previous
//
#include <hip/hip_runtime.h>
#include <math.h>

// Problem constants
#define BB   256    // batch
#define TT   1024   // timesteps
#define HH   512    // hidden
#define NWG  256    // 1 WG per CU
#define NTHR 512    // 8 waves
#define SLOT ((size_t)BB*HH)   // elements per h slot

typedef _Float16 f16;
typedef _Float16 f16x8 __attribute__((ext_vector_type(8)));
typedef float    f32x4 __attribute__((ext_vector_type(4)));

__device__ __forceinline__ f32x4 mf(f16x8 a, f16x8 b, f32x4 c){
  return __builtin_amdgcn_mfma_f32_16x16x32_f16(a, b, c, 0, 0, 0);
}

__device__ __forceinline__ float fast_sigmoid(float v){
  float e = __expf(-v);
  return __builtin_amdgcn_rcpf(1.0f + e);
}
__device__ __forceinline__ float fast_tanh(float v){
  float a = fabsf(v);
  float e = __expf(-2.0f * a);
  float r = (1.0f - e) * __builtin_amdgcn_rcpf(1.0f + e);
  return copysignf(r, v);
}

// hierarchical grid barrier: 8 spread counters (64B apart) -> master -> flag.
// ph is 1-based and strictly increasing.
__device__ __forceinline__ void gridbar(unsigned* bar, unsigned ph){
  __syncthreads();
  if (threadIdx.x == 0){
    __builtin_amdgcn_fence(__ATOMIC_RELEASE, "agent");
    unsigned g = blockIdx.x & 7u;
    unsigned old = __hip_atomic_fetch_add(&bar[g*16], 1u, __ATOMIC_RELAXED, __HIP_MEMORY_SCOPE_AGENT);
    if (old + 1u == 32u*ph){                       // last of the 32 WGs in this group
      unsigned om = __hip_atomic_fetch_add(&bar[128], 1u, __ATOMIC_RELAXED, __HIP_MEMORY_SCOPE_AGENT);
      if (om + 1u == 8u*ph){                       // last group
        __hip_atomic_store(&bar[160], ph, __ATOMIC_RELAXED, __HIP_MEMORY_SCOPE_AGENT);
      }
    }
    while (__hip_atomic_load(&bar[160], __ATOMIC_RELAXED, __HIP_MEMORY_SCOPE_AGENT) < ph){
      __builtin_amdgcn_s_sleep(2);
    }
    __builtin_amdgcn_fence(__ATOMIC_ACQUIRE, "agent");
  }
  __syncthreads();
}

// ws layout (bytes): [0,1K) barrier, [4K, 4K+1M) xT fp32 [T][B],
// then 4 f16 planes of 2 slots each: h1hi, h1lo, h2hi, h2lo ([slot][b][k], k contig).
__global__ __launch_bounds__(NTHR, 2) void lstm_mfma(
    const float* __restrict__ x,      const float* __restrict__ W_ih1,
    const float* __restrict__ W_hh1,  const float* __restrict__ b1,
    const float* __restrict__ W_ih2,  const float* __restrict__ W_hh2,
    const float* __restrict__ b2,     const float* __restrict__ W_lin,
    const float* __restrict__ b_lin,  float* __restrict__ out,
    char* __restrict__ wsb)
{
  // A fragments in exact MFMA layout: index [chunk*64 + lane], 16B each.
  // L2-tile (16 rows = 4 gates x 4 j of layer 2), K=1024 (h1 | h2): 32 chunks.
  // L1-tile (layer 1), K=512 (h1): 16 chunks.  hi/lo split planes.
  __shared__ f16x8 A2hi[2048], A2lo[2048], A1hi[1024], A1lo[1024]; // 96 KB
  __shared__ float xch[8][256];      // per-wave gate-exchange scratch (16 col x 16 row)
  __shared__ float wlin_s[512];
  __shared__ float outpart[2][8];

  unsigned* bar = (unsigned*)wsb;
  float* xT  = (float*)(wsb + 4096);
  f16* h1hi = (f16*)(wsb + 4096 + 1048576);
  f16* h1lo = h1hi + 2*SLOT;
  f16* h2hi = h1lo + 2*SLOT;
  f16* h2lo = h2hi + 2*SLOT;

  const int w   = blockIdx.x,  tid = threadIdx.x;
  const int l   = tid & 63,    wv  = tid >> 6;       // lane, wave
  const int quad = l >> 4,     lc  = l & 15;
  const int p = w >> 1, cb = w & 1;                  // row-group, batch half
  const int j0 = 4*p;                                // this WG's 4 hidden columns
  const int bcol = cb*128 + wv*16 + lc;              // this lane's batch column
  const int jq = j0 + quad;                          // this lane's j (post-exchange)

  // ---------------- init: weight split into LDS frag-order ----------------
  {
    const int g_ = lc >> 2, jj_ = lc & 3;            // A-row m = lc -> (gate, jj)
    const int wrow = g_*HH + j0 + jj_;
    const float* rowI  = W_ih2 + (size_t)wrow*HH;
    const float* rowH2 = W_hh2 + (size_t)wrow*HH;
    const float* rowH1 = W_hh1 + (size_t)wrow*HH;
    for (int c = wv; c < 32; c += 8){
      const int kb = c*32 + quad*8;
      union {f16x8 v; f16 e[8];} hi8, lo8;
      #pragma unroll
      for (int i = 0; i < 8; ++i){
        const int k = kb + i;
        const float wval = (k < HH) ? rowI[k] : rowH2[k - HH];
        const f16 h_ = (f16)wval;
        hi8.e[i] = h_;
        lo8.e[i] = (f16)((wval - (float)h_) * 2048.0f);
      }
      A2hi[c*64 + l] = hi8.v;
      A2lo[c*64 + l] = lo8.v;
    }
    for (int c = wv; c < 16; c += 8){
      const int kb = c*32 + quad*8;
      union {f16x8 v; f16 e[8];} hi8, lo8;
      #pragma unroll
      for (int i = 0; i < 8; ++i){
        const float wval = rowH1[kb + i];
        const f16 h_ = (f16)wval;
        hi8.e[i] = h_;
        lo8.e[i] = (f16)((wval - (float)h_) * 2048.0f);
      }
      A1hi[c*64 + l] = hi8.v;
      A1lo[c*64 + l] = lo8.v;
    }
  }
  // per-lane scalars (j = jq)
  float wih1r[4], b1r[4], b2r[4];
  #pragma unroll
  for (int g = 0; g < 4; ++g){
    wih1r[g] = W_ih1[g*HH + jq];
    b1r[g]   = b1[g*HH + jq];
    b2r[g]   = b2[g*HH + jq];
  }
  const float blin = b_lin[0];
  wlin_s[tid] = W_lin[tid];

  // x transpose -> xT[t][b]
  {
    const int gid = w*NTHR + tid;
    #pragma unroll
    for (int i2 = 0; i2 < 2; ++i2){
      const int idx = gid + i2*131072;
      const int bb2 = idx >> 10, tt2 = idx & (TT-1);
      xT[(size_t)tt2*BB + bb2] = x[idx];
    }
  }
  // zero h2 slot 1 (read as h2(-1) at t=0)
  h2hi[SLOT + (size_t)w*512 + tid] = (f16)0.0f;
  h2lo[SLOT + (size_t)w*512 + tid] = (f16)0.0f;

  gridbar(bar, 1);

  // ---------------- prologue: h1(0), c-state init ----------------
  float c1, c2 = 0.0f;
  {
    const float xv0 = xT[bcol];
    const float gi = fast_sigmoid(fmaf(xv0, wih1r[0], b1r[0]));
    const float gg = fast_tanh   (fmaf(xv0, wih1r[2], b1r[2]));
    const float go = fast_sigmoid(fmaf(xv0, wih1r[3], b1r[3]));
    c1 = gi * gg;
    const float hv = go * fast_tanh(c1);
    const size_t ho = (size_t)bcol*HH + jq;          // slot 0
    const f16 hh = (f16)hv;
    h1hi[ho] = hh;
    h1lo[ho] = (f16)((hv - (float)hh)*2048.0f);
  }
  gridbar(bar, 2);

  // ---------------- main loop: phase t computes h2(t), h1(t+1), out(t-1) ----------------
  for (int t = 0; t < TT; ++t){
    const size_t sR1 = (size_t)( t    & 1)*SLOT;     // h1(t)      (read)
    const size_t sR2 = (size_t)((t+1) & 1)*SLOT;     // h2(t-1)    (read)
    const size_t sW1 = (size_t)((t+1) & 1)*SLOT;     // h1(t+1)    (write)
    const size_t sW2 = (size_t)( t    & 1)*SLOT;     // h2(t)      (write)

    // out(t-1) partial: thread tid covers k = tid
    float opart;
    {
      const size_t oi = sR2 + (size_t)w*HH + tid;
      const float hv = (float)h2hi[oi] + (float)h2lo[oi]*(1.0f/2048.0f);
      opart = hv * wlin_s[tid];
    }

    f32x4 aA2 = {0,0,0,0}, aB2 = {0,0,0,0}, aA1 = {0,0,0,0}, aB1 = {0,0,0,0};
    const f16* p1h = h1hi + sR1 + (size_t)bcol*HH;
    const f16* p1l = h1lo + sR1 + (size_t)bcol*HH;
    const f16* p2h = h2hi + sR2 + (size_t)bcol*HH;
    const f16* p2l = h2lo + sR2 + (size_t)bcol*HH;

    #pragma unroll 4
    for (int c = 0; c < 16; ++c){                    // K-chunks over h1(t): feeds L2 and L1 tiles
      const int kof = c*32 + quad*8;
      const f16x8 bh = *(const f16x8*)(p1h + kof);
      const f16x8 bl = *(const f16x8*)(p1l + kof);
      const f16x8 a2h = A2hi[c*64 + l];
      const f16x8 a2l = A2lo[c*64 + l];
      const f16x8 a1h = A1hi[c*64 + l];
      const f16x8 a1l = A1lo[c*64 + l];
      aA2 = mf(a2h, bh, aA2);
      aB2 = mf(a2h, bl, aB2);
      aB2 = mf(a2l, bh, aB2);
      aA1 = mf(a1h, bh, aA1);
      aB1 = mf(a1h, bl, aB1);
      aB1 = mf(a1l, bh, aB1);
    }
    #pragma unroll 4
    for (int c = 16; c < 32; ++c){                   // K-chunks over h2(t-1): L2 tile only
      const int kof = (c-16)*32 + quad*8;
      const f16x8 bh = *(const f16x8*)(p2h + kof);
      const f16x8 bl = *(const f16x8*)(p2l + kof);
      const f16x8 a2h = A2hi[c*64 + l];
      const f16x8 a2l = A2lo[c*64 + l];
      aA2 = mf(a2h, bh, aA2);
      aB2 = mf(a2h, bl, aB2);
      aB2 = mf(a2l, bh, aB2);
    }

    float* xw = &xch[wv][0];
    // ---- layer-2 cell (lane -> jj=quad, b=bcol after exchange) ----
    {
      f32x4 pre;
      #pragma unroll
      for (int i = 0; i < 4; ++i) pre[i] = fmaf(aB2[i], 1.0f/2048.0f, aA2[i]);
      *(f32x4*)&xw[lc*16 + quad*4] = pre;            // [col][row] layout
      __threadfence_block();
      const float g0 = xw[lc*16 + 0*4 + quad];
      const float g1 = xw[lc*16 + 1*4 + quad];
      const float g2 = xw[lc*16 + 2*4 + quad];
      const float g3 = xw[lc*16 + 3*4 + quad];
      const float gi = fast_sigmoid(g0 + b2r[0]);
      const float gf = fast_sigmoid(g1 + b2r[1]);
      const float gg = fast_tanh   (g2 + b2r[2]);
      const float go = fast_sigmoid(g3 + b2r[3]);
      c2 = fmaf(gf, c2, gi*gg);
      const float hv = go * fast_tanh(c2);
      const size_t ho = sW2 + (size_t)bcol*HH + jq;
      const f16 hh = (f16)hv;
      h2hi[ho] = hh;
      h2lo[ho] = (f16)((hv - (float)hh)*2048.0f);
    }
    // ---- layer-1 cell (for t+1) ----
    {
      f32x4 pre;
      #pragma unroll
      for (int i = 0; i < 4; ++i) pre[i] = fmaf(aB1[i], 1.0f/2048.0f, aA1[i]);
      __threadfence_block();                          // prior reads done before overwrite
      *(f32x4*)&xw[lc*16 + quad*4] = pre;
      __threadfence_block();
      const float g0 = xw[lc*16 + 0*4 + quad];
      const float g1 = xw[lc*16 + 1*4 + quad];
      const float g2 = xw[lc*16 + 2*4 + quad];
      const float g3 = xw[lc*16 + 3*4 + quad];
      const int tx = (t+1 < TT) ? (t+1) : (TT-1);
      const float xv = xT[(size_t)tx*BB + bcol];
      const float gi = fast_sigmoid(g0 + fmaf(xv, wih1r[0], b1r[0]));
      const float gf = fast_sigmoid(g1 + fmaf(xv, wih1r[1], b1r[1]));
      const float gg = fast_tanh   (g2 + fmaf(xv, wih1r[2], b1r[2]));
      const float go = fast_sigmoid(g3 + fmaf(xv, wih1r[3], b1r[3]));
      c1 = fmaf(gf, c1, gi*gg);
      const float hv = go * fast_tanh(c1);
      const size_t ho = sW1 + (size_t)bcol*HH + jq;
      const f16 hh = (f16)hv;
      h1hi[ho] = hh;
      h1lo[ho] = (f16)((hv - (float)hh)*2048.0f);
    }
    // ---- out(t-1) reduce ----
    #pragma unroll
    for (int off = 32; off > 0; off >>= 1) opart += __shfl_down(opart, off, 64);
    if (l == 0) outpart[t & 1][wv] = opart;

    gridbar(bar, 3 + (unsigned)t);

    if (tid == 0 && t > 0){
      float s = blin;
      #pragma unroll
      for (int q2 = 0; q2 < 8; ++q2) s += outpart[t & 1][q2];
      out[(size_t)w*TT + (t-1)] = s;
    }
  }

  // ---------------- tail: out(1023) ----------------
  {
    const size_t oi = (size_t)((TT-1)&1)*SLOT + (size_t)w*HH + tid;
    const float hv = (float)h2hi[oi] + (float)h2lo[oi]*(1.0f/2048.0f);
    float opart = hv * wlin_s[tid];
    #pragma unroll
    for (int off = 32; off > 0; off >>= 1) opart += __shfl_down(opart, off, 64);
    if (l == 0) outpart[0][wv] = opart;
    __syncthreads();
    if (tid == 0){
      float s = blin;
      #pragma unroll
      for (int q2 = 0; q2 < 8; ++q2) s += outpart[0][q2];
      out[(size_t)w*TT + (TT-1)] = s;
    }
  }
}

extern "C" void kernel_launch(void* const* d_in, const int* in_sizes, int n_in,
                              void* d_out, int out_size, void* d_ws, size_t ws_size,
                              hipStream_t stream) {
  const float* x     = (const float*)d_in[0];
  const float* W_ih1 = (const float*)d_in[1];
  const float* W_hh1 = (const float*)d_in[2];
  const float* b1    = (const float*)d_in[3];
  const float* W_ih2 = (const float*)d_in[4];
  const float* W_hh2 = (const float*)d_in[5];
  const float* b2    = (const float*)d_in[6];
  const float* W_lin = (const float*)d_in[7];
  const float* b_lin = (const float*)d_in[8];
  float* out = (float*)d_out;
  char* wsb  = (char*)d_ws;

  // zero the barrier counters (ws is re-poisoned to 0xAA before every launch)
  hipMemsetAsync(d_ws, 0, 1024, stream);

  hipLaunchKernelGGL(lstm_mfma, dim3(NWG), dim3(NTHR), 0, stream,
                     x, W_ih1, W_hh1, b1, W_ih2, W_hh2, b2, W_lin, b_lin, out, wsb);
}

// Round 3
// 21284.570 us; speedup vs baseline: 6.1604x; 1.2663x over previous
//
#include <hip/hip_runtime.h>
#include <math.h>

// Problem constants
#define BB   256    // batch
#define TT   1024   // timesteps
#define HH   512    // hidden
#define NWG  256    // 1 WG per CU
#define NTHR 512    // 8 waves
#define SLOT ((size_t)BB*HH)   // elements per h slot

typedef _Float16 f16;
typedef _Float16 f16x8 __attribute__((ext_vector_type(8)));
typedef float    f32x4 __attribute__((ext_vector_type(4)));

__device__ __forceinline__ f32x4 mf(f16x8 a, f16x8 b, f32x4 c){
  return __builtin_amdgcn_mfma_f32_16x16x32_f16(a, b, c, 0, 0, 0);
}

__device__ __forceinline__ float fast_sigmoid(float v){
  float e = __expf(-v);
  return __builtin_amdgcn_rcpf(1.0f + e);
}
__device__ __forceinline__ float fast_tanh(float v){
  float a = fabsf(v);
  float e = __expf(-2.0f * a);
  float r = (1.0f - e) * __builtin_amdgcn_rcpf(1.0f + e);
  return copysignf(r, v);
}

// write-through (device-coherent) f16 store: bypasses L2 dirty state, lands at L3.
__device__ __forceinline__ void st_f16_wt(f16* p, f16 v){
  union { f16 f; unsigned short u; } cv; cv.f = v;
  __hip_atomic_store((unsigned short*)p, cv.u, __ATOMIC_RELAXED, __HIP_MEMORY_SCOPE_AGENT);
}

// hierarchical grid barrier: 8 spread counters (64B apart) -> master -> flag.
// ph is 1-based and strictly increasing. Release fence's wbl2 is cheap now:
// all cross-visible stores are write-through, L2 stays clean.
__device__ __forceinline__ void gridbar(unsigned* bar, unsigned ph){
  __syncthreads();
  if (threadIdx.x == 0){
    __builtin_amdgcn_fence(__ATOMIC_RELEASE, "agent");
    unsigned g = blockIdx.x & 7u;
    unsigned old = __hip_atomic_fetch_add(&bar[g*16], 1u, __ATOMIC_RELAXED, __HIP_MEMORY_SCOPE_AGENT);
    if (old + 1u == 32u*ph){                       // last of the 32 WGs in this group
      unsigned om = __hip_atomic_fetch_add(&bar[128], 1u, __ATOMIC_RELAXED, __HIP_MEMORY_SCOPE_AGENT);
      if (om + 1u == 8u*ph){                       // last group
        __hip_atomic_store(&bar[160], ph, __ATOMIC_RELAXED, __HIP_MEMORY_SCOPE_AGENT);
      }
    }
    while (__hip_atomic_load(&bar[160], __ATOMIC_RELAXED, __HIP_MEMORY_SCOPE_AGENT) < ph){
      __builtin_amdgcn_s_sleep(2);
    }
    __builtin_amdgcn_fence(__ATOMIC_ACQUIRE, "agent");
  }
  __syncthreads();
}

// ws layout (bytes): [0,1K) barrier, [4K, 4K+1M) xT fp32 [T][B],
// then 4 f16 planes of 2 slots each: h1hi, h1lo, h2hi, h2lo ([slot][b][k], k contig).
__global__ __launch_bounds__(NTHR, 2) void lstm_mfma(
    const float* __restrict__ x,      const float* __restrict__ W_ih1,
    const float* __restrict__ W_hh1,  const float* __restrict__ b1,
    const float* __restrict__ W_ih2,  const float* __restrict__ W_hh2,
    const float* __restrict__ b2,     const float* __restrict__ W_lin,
    const float* __restrict__ b_lin,  float* __restrict__ out,
    char* __restrict__ wsb)
{
  // A fragments in exact MFMA layout: index [chunk*64 + lane], 16B each.
  // L2-tile (16 rows = 4 gates x 4 j of layer 2), K=1024 (h1 | h2): 32 chunks.
  // L1-tile (layer 1), K=512 (h1): 16 chunks.  hi/lo split planes.
  __shared__ f16x8 A2hi[2048], A2lo[2048], A1hi[1024], A1lo[1024]; // 96 KB
  __shared__ float xch[8][256];      // per-wave gate-exchange scratch (16 col x 16 row)
  __shared__ float wlin_s[512];
  __shared__ float outpart[2][8];

  unsigned* bar = (unsigned*)wsb;
  float* xT  = (float*)(wsb + 4096);
  f16* h1hi = (f16*)(wsb + 4096 + 1048576);
  f16* h1lo = h1hi + 2*SLOT;
  f16* h2hi = h1lo + 2*SLOT;
  f16* h2lo = h2hi + 2*SLOT;

  const int w   = blockIdx.x,  tid = threadIdx.x;
  const int l   = tid & 63,    wv  = tid >> 6;       // lane, wave
  const int quad = l >> 4,     lc  = l & 15;
  const int p = w >> 1, cb = w & 1;                  // row-group, batch half
  const int j0 = 4*p;                                // this WG's 4 hidden columns
  const int bcol = cb*128 + wv*16 + lc;              // this lane's batch column
  const int jq = j0 + quad;                          // this lane's j (post-exchange)

  // ---------------- init: weight split into LDS frag-order ----------------
  {
    const int g_ = lc >> 2, jj_ = lc & 3;            // A-row m = lc -> (gate, jj)
    const int wrow = g_*HH + j0 + jj_;
    const float* rowI  = W_ih2 + (size_t)wrow*HH;
    const float* rowH2 = W_hh2 + (size_t)wrow*HH;
    const float* rowH1 = W_hh1 + (size_t)wrow*HH;
    for (int c = wv; c < 32; c += 8){
      const int kb = c*32 + quad*8;
      union {f16x8 v; f16 e[8];} hi8, lo8;
      #pragma unroll
      for (int i = 0; i < 8; ++i){
        const int k = kb + i;
        const float wval = (k < HH) ? rowI[k] : rowH2[k - HH];
        const f16 h_ = (f16)wval;
        hi8.e[i] = h_;
        lo8.e[i] = (f16)((wval - (float)h_) * 2048.0f);
      }
      A2hi[c*64 + l] = hi8.v;
      A2lo[c*64 + l] = lo8.v;
    }
    for (int c = wv; c < 16; c += 8){
      const int kb = c*32 + quad*8;
      union {f16x8 v; f16 e[8];} hi8, lo8;
      #pragma unroll
      for (int i = 0; i < 8; ++i){
        const float wval = rowH1[kb + i];
        const f16 h_ = (f16)wval;
        hi8.e[i] = h_;
        lo8.e[i] = (f16)((wval - (float)h_) * 2048.0f);
      }
      A1hi[c*64 + l] = hi8.v;
      A1lo[c*64 + l] = lo8.v;
    }
  }
  // per-lane scalars (j = jq)
  float wih1r[4], b1r[4], b2r[4];
  #pragma unroll
  for (int g = 0; g < 4; ++g){
    wih1r[g] = W_ih1[g*HH + jq];
    b1r[g]   = b1[g*HH + jq];
    b2r[g]   = b2[g*HH + jq];
  }
  const float blin = b_lin[0];
  wlin_s[tid] = W_lin[tid];

  // x transpose -> xT[t][b]
  {
    const int gid = w*NTHR + tid;
    #pragma unroll
    for (int i2 = 0; i2 < 2; ++i2){
      const int idx = gid + i2*131072;
      const int bb2 = idx >> 10, tt2 = idx & (TT-1);
      xT[(size_t)tt2*BB + bb2] = x[idx];
    }
  }
  // zero h2 slot 1 (read as h2(-1) at t=0) — write-through
  st_f16_wt(&h2hi[SLOT + (size_t)w*512 + tid], (f16)0.0f);
  st_f16_wt(&h2lo[SLOT + (size_t)w*512 + tid], (f16)0.0f);

  gridbar(bar, 1);

  // ---------------- prologue: h1(0), c-state init ----------------
  float c1, c2 = 0.0f;
  {
    const float xv0 = xT[bcol];
    const float gi = fast_sigmoid(fmaf(xv0, wih1r[0], b1r[0]));
    const float gg = fast_tanh   (fmaf(xv0, wih1r[2], b1r[2]));
    const float go = fast_sigmoid(fmaf(xv0, wih1r[3], b1r[3]));
    c1 = gi * gg;
    const float hv = go * fast_tanh(c1);
    const size_t ho = (size_t)bcol*HH + jq;          // slot 0
    const f16 hh = (f16)hv;
    st_f16_wt(&h1hi[ho], hh);
    st_f16_wt(&h1lo[ho], (f16)((hv - (float)hh)*2048.0f));
  }
  gridbar(bar, 2);

  // ---------------- main loop: phase t computes h2(t), h1(t+1), out(t-1) ----------------
  for (int t = 0; t < TT; ++t){
    const size_t sR1 = (size_t)( t    & 1)*SLOT;     // h1(t)      (read)
    const size_t sR2 = (size_t)((t+1) & 1)*SLOT;     // h2(t-1)    (read)
    const size_t sW1 = (size_t)((t+1) & 1)*SLOT;     // h1(t+1)    (write)
    const size_t sW2 = (size_t)( t    & 1)*SLOT;     // h2(t)      (write)

    // out(t-1) partial: thread tid covers k = tid
    float opart;
    {
      const size_t oi = sR2 + (size_t)w*HH + tid;
      const float hv = (float)h2hi[oi] + (float)h2lo[oi]*(1.0f/2048.0f);
      opart = hv * wlin_s[tid];
    }

    f32x4 aA2 = {0,0,0,0}, aB2 = {0,0,0,0}, aA1 = {0,0,0,0}, aB1 = {0,0,0,0};
    const f16* p1h = h1hi + sR1 + (size_t)bcol*HH;
    const f16* p1l = h1lo + sR1 + (size_t)bcol*HH;
    const f16* p2h = h2hi + sR2 + (size_t)bcol*HH;
    const f16* p2l = h2lo + sR2 + (size_t)bcol*HH;

    #pragma unroll 4
    for (int c = 0; c < 16; ++c){                    // K-chunks over h1(t): feeds L2 and L1 tiles
      const int kof = c*32 + quad*8;
      const f16x8 bh = *(const f16x8*)(p1h + kof);
      const f16x8 bl = *(const f16x8*)(p1l + kof);
      const f16x8 a2h = A2hi[c*64 + l];
      const f16x8 a2l = A2lo[c*64 + l];
      const f16x8 a1h = A1hi[c*64 + l];
      const f16x8 a1l = A1lo[c*64 + l];
      aA2 = mf(a2h, bh, aA2);
      aB2 = mf(a2h, bl, aB2);
      aB2 = mf(a2l, bh, aB2);
      aA1 = mf(a1h, bh, aA1);
      aB1 = mf(a1h, bl, aB1);
      aB1 = mf(a1l, bh, aB1);
    }
    #pragma unroll 4
    for (int c = 16; c < 32; ++c){                   // K-chunks over h2(t-1): L2 tile only
      const int kof = (c-16)*32 + quad*8;
      const f16x8 bh = *(const f16x8*)(p2h + kof);
      const f16x8 bl = *(const f16x8*)(p2l + kof);
      const f16x8 a2h = A2hi[c*64 + l];
      const f16x8 a2l = A2lo[c*64 + l];
      aA2 = mf(a2h, bh, aA2);
      aB2 = mf(a2h, bl, aB2);
      aB2 = mf(a2l, bh, aB2);
    }

    float* xw = &xch[wv][0];
    // ---- layer-2 cell (lane -> jj=quad, b=bcol after exchange) ----
    {
      f32x4 pre;
      #pragma unroll
      for (int i = 0; i < 4; ++i) pre[i] = fmaf(aB2[i], 1.0f/2048.0f, aA2[i]);
      *(f32x4*)&xw[lc*16 + quad*4] = pre;            // [col][row] layout
      __threadfence_block();
      const float g0 = xw[lc*16 + 0*4 + quad];
      const float g1 = xw[lc*16 + 1*4 + quad];
      const float g2 = xw[lc*16 + 2*4 + quad];
      const float g3 = xw[lc*16 + 3*4 + quad];
      const float gi = fast_sigmoid(g0 + b2r[0]);
      const float gf = fast_sigmoid(g1 + b2r[1]);
      const float gg = fast_tanh   (g2 + b2r[2]);
      const float go = fast_sigmoid(g3 + b2r[3]);
      c2 = fmaf(gf, c2, gi*gg);
      const float hv = go * fast_tanh(c2);
      const size_t ho = sW2 + (size_t)bcol*HH + jq;
      const f16 hh = (f16)hv;
      st_f16_wt(&h2hi[ho], hh);
      st_f16_wt(&h2lo[ho], (f16)((hv - (float)hh)*2048.0f));
    }
    // ---- layer-1 cell (for t+1) ----
    {
      f32x4 pre;
      #pragma unroll
      for (int i = 0; i < 4; ++i) pre[i] = fmaf(aB1[i], 1.0f/2048.0f, aA1[i]);
      __threadfence_block();                          // prior reads done before overwrite
      *(f32x4*)&xw[lc*16 + quad*4] = pre;
      __threadfence_block();
      const float g0 = xw[lc*16 + 0*4 + quad];
      const float g1 = xw[lc*16 + 1*4 + quad];
      const float g2 = xw[lc*16 + 2*4 + quad];
      const float g3 = xw[lc*16 + 3*4 + quad];
      const int tx = (t+1 < TT) ? (t+1) : (TT-1);
      const float xv = xT[(size_t)tx*BB + bcol];
      const float gi = fast_sigmoid(g0 + fmaf(xv, wih1r[0], b1r[0]));
      const float gf = fast_sigmoid(g1 + fmaf(xv, wih1r[1], b1r[1]));
      const float gg = fast_tanh   (g2 + fmaf(xv, wih1r[2], b1r[2]));
      const float go = fast_sigmoid(g3 + fmaf(xv, wih1r[3], b1r[3]));
      c1 = fmaf(gf, c1, gi*gg);
      const float hv = go * fast_tanh(c1);
      const size_t ho = sW1 + (size_t)bcol*HH + jq;
      const f16 hh = (f16)hv;
      st_f16_wt(&h1hi[ho], hh);
      st_f16_wt(&h1lo[ho], (f16)((hv - (float)hh)*2048.0f));
    }
    // ---- out(t-1) reduce ----
    #pragma unroll
    for (int off = 32; off > 0; off >>= 1) opart += __shfl_down(opart, off, 64);
    if (l == 0) outpart[t & 1][wv] = opart;

    gridbar(bar, 3 + (unsigned)t);

    if (tid == 0 && t > 0){
      float s = blin;
      #pragma unroll
      for (int q2 = 0; q2 < 8; ++q2) s += outpart[t & 1][q2];
      __hip_atomic_store(&out[(size_t)w*TT + (t-1)], s,
                         __ATOMIC_RELAXED, __HIP_MEMORY_SCOPE_AGENT);
    }
  }

  // ---------------- tail: out(1023) ----------------
  {
    const size_t oi = (size_t)((TT-1)&1)*SLOT + (size_t)w*HH + tid;
    const float hv = (float)h2hi[oi] + (float)h2lo[oi]*(1.0f/2048.0f);
    float opart = hv * wlin_s[tid];
    #pragma unroll
    for (int off = 32; off > 0; off >>= 1) opart += __shfl_down(opart, off, 64);
    if (l == 0) outpart[0][wv] = opart;
    __syncthreads();
    if (tid == 0){
      float s = blin;
      #pragma unroll
      for (int q2 = 0; q2 < 8; ++q2) s += outpart[0][q2];
      __hip_atomic_store(&out[(size_t)w*TT + (TT-1)], s,
                         __ATOMIC_RELAXED, __HIP_MEMORY_SCOPE_AGENT);
    }
  }
}

extern "C" void kernel_launch(void* const* d_in, const int* in_sizes, int n_in,
                              void* d_out, int out_size, void* d_ws, size_t ws_size,
                              hipStream_t stream) {
  const float* x     = (const float*)d_in[0];
  const float* W_ih1 = (const float*)d_in[1];
  const float* W_hh1 = (const float*)d_in[2];
  const float* b1    = (const float*)d_in[3];
  const float* W_ih2 = (const float*)d_in[4];
  const float* W_hh2 = (const float*)d_in[5];
  const float* b2    = (const float*)d_in[6];
  const float* W_lin = (const float*)d_in[7];
  const float* b_lin = (const float*)d_in[8];
  float* out = (float*)d_out;
  char* wsb  = (char*)d_ws;

  // zero the barrier counters (ws is re-poisoned to 0xAA before every launch)
  hipMemsetAsync(d_ws, 0, 1024, stream);

  hipLaunchKernelGGL(lstm_mfma, dim3(NWG), dim3(NTHR), 0, stream,
                     x, W_ih1, W_hh1, b1, W_ih2, W_hh2, b2, W_lin, b_lin, out, wsb);
}

// Round 4
// 20929.932 us; speedup vs baseline: 6.2648x; 1.0169x over previous
//
#include <hip/hip_runtime.h>
#include <math.h>

// Problem constants
#define BB   256    // batch
#define TT   1024   // timesteps
#define HH   512    // hidden
#define NWG  256    // 1 WG per CU
#define NTHR 512    // 8 waves
#define SLOT ((size_t)BB*HH)   // elements per h slot

typedef _Float16 f16;
typedef _Float16 f16x8 __attribute__((ext_vector_type(8)));
typedef float    f32x4 __attribute__((ext_vector_type(4)));

__device__ __forceinline__ f32x4 mf(f16x8 a, f16x8 b, f32x4 c){
  return __builtin_amdgcn_mfma_f32_16x16x32_f16(a, b, c, 0, 0, 0);
}

__device__ __forceinline__ float fast_sigmoid(float v){
  float e = __expf(-v);
  return __builtin_amdgcn_rcpf(1.0f + e);
}
__device__ __forceinline__ float fast_tanh(float v){
  float a = fabsf(v);
  float e = __expf(-2.0f * a);
  float r = (1.0f - e) * __builtin_amdgcn_rcpf(1.0f + e);
  return copysignf(r, v);
}

// write-through (device-coherent) f16 store: bypasses L2 dirty state, lands at L3.
__device__ __forceinline__ void st_f16_wt(f16* p, f16 v){
  union { f16 f; unsigned short u; } cv; cv.f = v;
  __hip_atomic_store((unsigned short*)p, cv.u, __ATOMIC_RELAXED, __HIP_MEMORY_SCOPE_AGENT);
}

// hierarchical grid barrier with DISTRIBUTED release flags:
// arrival: 32 group counters (8 WGs each, 64B apart) -> master -> 32 flag replicas.
// Each WG polls only its own replica (<=8 pollers per cacheline -> no hot-spot).
// bar layout (unsigned words): [g*16] 32 group counters, [512] master, [544+r*16] 32 flags.
__device__ __forceinline__ void gridbar(unsigned* bar, unsigned ph){
  __syncthreads();
  if (threadIdx.x == 0){
    __builtin_amdgcn_fence(__ATOMIC_RELEASE, "agent");
    const unsigned g = blockIdx.x & 31u;
    unsigned old = __hip_atomic_fetch_add(&bar[g*16], 1u, __ATOMIC_RELAXED, __HIP_MEMORY_SCOPE_AGENT);
    if (old + 1u == 8u*ph){                        // last of the 8 WGs in this group
      unsigned om = __hip_atomic_fetch_add(&bar[512], 1u, __ATOMIC_RELAXED, __HIP_MEMORY_SCOPE_AGENT);
      if (om + 1u == 32u*ph){                      // last group -> publish to all replicas
        #pragma unroll
        for (int r = 0; r < 32; ++r)
          __hip_atomic_store(&bar[544 + r*16], ph, __ATOMIC_RELAXED, __HIP_MEMORY_SCOPE_AGENT);
      }
    }
    while (__hip_atomic_load(&bar[544 + g*16], __ATOMIC_RELAXED, __HIP_MEMORY_SCOPE_AGENT) < ph){
      __builtin_amdgcn_s_sleep(2);
    }
    __builtin_amdgcn_fence(__ATOMIC_ACQUIRE, "agent");
  }
  __syncthreads();
}

// ws layout (bytes): [0,8K) barrier, [8K, 8K+1M) xT fp32 [T][B],
// then 4 f16 planes of 2 slots each: h1hi, h1lo, h2hi, h2lo ([slot][b][k], k contig).
__global__ __launch_bounds__(NTHR, 2) void lstm_mfma(
    const float* __restrict__ x,      const float* __restrict__ W_ih1,
    const float* __restrict__ W_hh1,  const float* __restrict__ b1,
    const float* __restrict__ W_ih2,  const float* __restrict__ W_hh2,
    const float* __restrict__ b2,     const float* __restrict__ W_lin,
    const float* __restrict__ b_lin,  float* __restrict__ out,
    char* __restrict__ wsb)
{
  // A fragments in exact MFMA layout: index [chunk*64 + lane], 16B each.
  __shared__ f16x8 A2hi[2048], A2lo[2048], A1hi[1024], A1lo[1024]; // 96 KB
  __shared__ float xch[8][256];      // per-wave gate-exchange scratch
  __shared__ float wlin_s[512];
  __shared__ float outpart[2][8];

  unsigned* bar = (unsigned*)wsb;
  float* xT  = (float*)(wsb + 8192);
  f16* h1hi = (f16*)(wsb + 8192 + 1048576);
  f16* h1lo = h1hi + 2*SLOT;
  f16* h2hi = h1lo + 2*SLOT;
  f16* h2lo = h2hi + 2*SLOT;

  const int w   = blockIdx.x,  tid = threadIdx.x;
  const int l   = tid & 63,    wv  = tid >> 6;       // lane, wave
  const int quad = l >> 4,     lc  = l & 15;
  const int p = w >> 1, cb = w & 1;                  // row-group, batch half
  const int j0 = 4*p;                                // this WG's 4 hidden columns
  const int bcol = cb*128 + wv*16 + lc;              // this lane's batch column
  const int jq = j0 + quad;                          // this lane's j (post-exchange)

  // ---------------- init: weight split into LDS frag-order ----------------
  {
    const int g_ = lc >> 2, jj_ = lc & 3;            // A-row m = lc -> (gate, jj)
    const int wrow = g_*HH + j0 + jj_;
    const float* rowI  = W_ih2 + (size_t)wrow*HH;
    const float* rowH2 = W_hh2 + (size_t)wrow*HH;
    const float* rowH1 = W_hh1 + (size_t)wrow*HH;
    for (int c = wv; c < 32; c += 8){
      const int kb = c*32 + quad*8;
      union {f16x8 v; f16 e[8];} hi8, lo8;
      #pragma unroll
      for (int i = 0; i < 8; ++i){
        const int k = kb + i;
        const float wval = (k < HH) ? rowI[k] : rowH2[k - HH];
        const f16 h_ = (f16)wval;
        hi8.e[i] = h_;
        lo8.e[i] = (f16)((wval - (float)h_) * 2048.0f);
      }
      A2hi[c*64 + l] = hi8.v;
      A2lo[c*64 + l] = lo8.v;
    }
    for (int c = wv; c < 16; c += 8){
      const int kb = c*32 + quad*8;
      union {f16x8 v; f16 e[8];} hi8, lo8;
      #pragma unroll
      for (int i = 0; i < 8; ++i){
        const float wval = rowH1[kb + i];
        const f16 h_ = (f16)wval;
        hi8.e[i] = h_;
        lo8.e[i] = (f16)((wval - (float)h_) * 2048.0f);
      }
      A1hi[c*64 + l] = hi8.v;
      A1lo[c*64 + l] = lo8.v;
    }
  }
  // per-lane scalars (j = jq)
  float wih1r[4], b1r[4], b2r[4];
  #pragma unroll
  for (int g = 0; g < 4; ++g){
    wih1r[g] = W_ih1[g*HH + jq];
    b1r[g]   = b1[g*HH + jq];
    b2r[g]   = b2[g*HH + jq];
  }
  const float blin = b_lin[0];
  wlin_s[tid] = W_lin[tid];

  // x transpose -> xT[t][b]
  {
    const int gid = w*NTHR + tid;
    #pragma unroll
    for (int i2 = 0; i2 < 2; ++i2){
      const int idx = gid + i2*131072;
      const int bb2 = idx >> 10, tt2 = idx & (TT-1);
      xT[(size_t)tt2*BB + bb2] = x[idx];
    }
  }
  // zero h2 slot 1 (read as h2(-1) at t=0) — write-through
  st_f16_wt(&h2hi[SLOT + (size_t)w*512 + tid], (f16)0.0f);
  st_f16_wt(&h2lo[SLOT + (size_t)w*512 + tid], (f16)0.0f);

  gridbar(bar, 1);

  // ---------------- prologue: h1(0), c-state init ----------------
  float c1, c2 = 0.0f;
  {
    const float xv0 = xT[bcol];
    const float gi = fast_sigmoid(fmaf(xv0, wih1r[0], b1r[0]));
    const float gg = fast_tanh   (fmaf(xv0, wih1r[2], b1r[2]));
    const float go = fast_sigmoid(fmaf(xv0, wih1r[3], b1r[3]));
    c1 = gi * gg;
    const float hv = go * fast_tanh(c1);
    const size_t ho = (size_t)bcol*HH + jq;          // slot 0
    const f16 hh = (f16)hv;
    st_f16_wt(&h1hi[ho], hh);
    st_f16_wt(&h1lo[ho], (f16)((hv - (float)hh)*2048.0f));
  }
  gridbar(bar, 2);

  // ---------------- main loop: phase t computes h2(t), h1(t+1), out(t-1) ----------------
  for (int t = 0; t < TT; ++t){
    const size_t sR1 = (size_t)( t    & 1)*SLOT;     // h1(t)      (read)
    const size_t sR2 = (size_t)((t+1) & 1)*SLOT;     // h2(t-1)    (read)
    const size_t sW1 = (size_t)((t+1) & 1)*SLOT;     // h1(t+1)    (write)
    const size_t sW2 = (size_t)( t    & 1)*SLOT;     // h2(t)      (write)

    const f16* p1h = h1hi + sR1 + (size_t)bcol*HH + quad*8;
    const f16* p1l = h1lo + sR1 + (size_t)bcol*HH + quad*8;
    const f16* p2h = h2hi + sR2 + (size_t)bcol*HH + quad*8;
    const f16* p2l = h2lo + sR2 + (size_t)bcol*HH + quad*8;

    // ---- burst-load ALL h1 chunks (32 x 16B loads in flight) ----
    f16x8 b1hv[16], b1lv[16];
    #pragma unroll
    for (int c = 0; c < 16; ++c){
      b1hv[c] = *(const f16x8*)(p1h + c*32);
      b1lv[c] = *(const f16x8*)(p1l + c*32);
    }

    // out(t-1) partial: thread tid covers k = tid
    float opart;
    {
      const size_t oi = sR2 + (size_t)w*HH + tid;
      const float hv = (float)h2hi[oi] + (float)h2lo[oi]*(1.0f/2048.0f);
      opart = hv * wlin_s[tid];
    }

    f32x4 aA2 = {0,0,0,0}, aB2 = {0,0,0,0}, aA1 = {0,0,0,0}, aB1 = {0,0,0,0};

    // ---- h1 MFMA loop; interleave h2 loads (pipeline) ----
    f16x8 b2hv[16], b2lv[16];
    #pragma unroll
    for (int c = 0; c < 16; ++c){
      b2hv[c] = *(const f16x8*)(p2h + c*32);
      b2lv[c] = *(const f16x8*)(p2l + c*32);
      const f16x8 a2h = A2hi[c*64 + l];
      const f16x8 a2l = A2lo[c*64 + l];
      const f16x8 a1h = A1hi[c*64 + l];
      const f16x8 a1l = A1lo[c*64 + l];
      aA2 = mf(a2h, b1hv[c], aA2);
      aB2 = mf(a2h, b1lv[c], aB2);
      aB2 = mf(a2l, b1hv[c], aB2);
      aA1 = mf(a1h, b1hv[c], aA1);
      aB1 = mf(a1h, b1lv[c], aB1);
      aB1 = mf(a1l, b1hv[c], aB1);
    }
    // ---- h2 MFMA loop ----
    #pragma unroll
    for (int c = 0; c < 16; ++c){
      const f16x8 a2h = A2hi[(c+16)*64 + l];
      const f16x8 a2l = A2lo[(c+16)*64 + l];
      aA2 = mf(a2h, b2hv[c], aA2);
      aB2 = mf(a2h, b2lv[c], aB2);
      aB2 = mf(a2l, b2hv[c], aB2);
    }

    float* xw = &xch[wv][0];
    // ---- layer-2 cell (lane -> jj=quad, b=bcol after exchange) ----
    {
      f32x4 pre;
      #pragma unroll
      for (int i = 0; i < 4; ++i) pre[i] = fmaf(aB2[i], 1.0f/2048.0f, aA2[i]);
      *(f32x4*)&xw[lc*16 + quad*4] = pre;            // [col][row] layout
      __threadfence_block();
      const float g0 = xw[lc*16 + 0*4 + quad];
      const float g1 = xw[lc*16 + 1*4 + quad];
      const float g2 = xw[lc*16 + 2*4 + quad];
      const float g3 = xw[lc*16 + 3*4 + quad];
      const float gi = fast_sigmoid(g0 + b2r[0]);
      const float gf = fast_sigmoid(g1 + b2r[1]);
      const float gg = fast_tanh   (g2 + b2r[2]);
      const float go = fast_sigmoid(g3 + b2r[3]);
      c2 = fmaf(gf, c2, gi*gg);
      const float hv = go * fast_tanh(c2);
      const size_t ho = sW2 + (size_t)bcol*HH + jq;
      const f16 hh = (f16)hv;
      st_f16_wt(&h2hi[ho], hh);
      st_f16_wt(&h2lo[ho], (f16)((hv - (float)hh)*2048.0f));
    }
    // ---- layer-1 cell (for t+1) ----
    {
      f32x4 pre;
      #pragma unroll
      for (int i = 0; i < 4; ++i) pre[i] = fmaf(aB1[i], 1.0f/2048.0f, aA1[i]);
      __threadfence_block();                          // prior reads done before overwrite
      *(f32x4*)&xw[lc*16 + quad*4] = pre;
      __threadfence_block();
      const float g0 = xw[lc*16 + 0*4 + quad];
      const float g1 = xw[lc*16 + 1*4 + quad];
      const float g2 = xw[lc*16 + 2*4 + quad];
      const float g3 = xw[lc*16 + 3*4 + quad];
      const int tx = (t+1 < TT) ? (t+1) : (TT-1);
      const float xv = xT[(size_t)tx*BB + bcol];
      const float gi = fast_sigmoid(g0 + fmaf(xv, wih1r[0], b1r[0]));
      const float gf = fast_sigmoid(g1 + fmaf(xv, wih1r[1], b1r[1]));
      const float gg = fast_tanh   (g2 + fmaf(xv, wih1r[2], b1r[2]));
      const float go = fast_sigmoid(g3 + fmaf(xv, wih1r[3], b1r[3]));
      c1 = fmaf(gf, c1, gi*gg);
      const float hv = go * fast_tanh(c1);
      const size_t ho = sW1 + (size_t)bcol*HH + jq;
      const f16 hh = (f16)hv;
      st_f16_wt(&h1hi[ho], hh);
      st_f16_wt(&h1lo[ho], (f16)((hv - (float)hh)*2048.0f));
    }
    // ---- out(t-1) reduce ----
    #pragma unroll
    for (int off = 32; off > 0; off >>= 1) opart += __shfl_down(opart, off, 64);
    if (l == 0) outpart[t & 1][wv] = opart;

    gridbar(bar, 3 + (unsigned)t);

    if (tid == 0 && t > 0){
      float s = blin;
      #pragma unroll
      for (int q2 = 0; q2 < 8; ++q2) s += outpart[t & 1][q2];
      __hip_atomic_store(&out[(size_t)w*TT + (t-1)], s,
                         __ATOMIC_RELAXED, __HIP_MEMORY_SCOPE_AGENT);
    }
  }

  // ---------------- tail: out(1023) ----------------
  {
    const size_t oi = (size_t)((TT-1)&1)*SLOT + (size_t)w*HH + tid;
    const float hv = (float)h2hi[oi] + (float)h2lo[oi]*(1.0f/2048.0f);
    float opart = hv * wlin_s[tid];
    #pragma unroll
    for (int off = 32; off > 0; off >>= 1) opart += __shfl_down(opart, off, 64);
    if (l == 0) outpart[0][wv] = opart;
    __syncthreads();
    if (tid == 0){
      float s = blin;
      #pragma unroll
      for (int q2 = 0; q2 < 8; ++q2) s += outpart[0][q2];
      __hip_atomic_store(&out[(size_t)w*TT + (TT-1)], s,
                         __ATOMIC_RELAXED, __HIP_MEMORY_SCOPE_AGENT);
    }
  }
}

extern "C" void kernel_launch(void* const* d_in, const int* in_sizes, int n_in,
                              void* d_out, int out_size, void* d_ws, size_t ws_size,
                              hipStream_t stream) {
  const float* x     = (const float*)d_in[0];
  const float* W_ih1 = (const float*)d_in[1];
  const float* W_hh1 = (const float*)d_in[2];
  const float* b1    = (const float*)d_in[3];
  const float* W_ih2 = (const float*)d_in[4];
  const float* W_hh2 = (const float*)d_in[5];
  const float* b2    = (const float*)d_in[6];
  const float* W_lin = (const float*)d_in[7];
  const float* b_lin = (const float*)d_in[8];
  float* out = (float*)d_out;
  char* wsb  = (char*)d_ws;

  // zero the barrier region (ws is re-poisoned to 0xAA before every launch)
  hipMemsetAsync(d_ws, 0, 8192, stream);

  hipLaunchKernelGGL(lstm_mfma, dim3(NWG), dim3(NTHR), 0, stream,
                     x, W_ih1, W_hh1, b1, W_ih2, W_hh2, b2, W_lin, b_lin, out, wsb);
}